// Round 1
// baseline (324.210 us; speedup 1.0000x reference)
//
#include <hip/hip_runtime.h>
#include <hip/hip_bf16.h>

#define B_  4
#define S_  2048
#define H_  1024
#define NH_ 16
#define HD_ 64

typedef __bf16 bf16;
typedef __attribute__((ext_vector_type(8))) __bf16 bf16x8;
typedef __attribute__((ext_vector_type(4))) __bf16 bf16x4;
typedef __attribute__((ext_vector_type(4))) float f32x4;

typedef const __attribute__((address_space(1))) char* gptr_t;
typedef __attribute__((address_space(3))) char* lptr_t;
#define GLOAD_LDS16(g, l) __builtin_amdgcn_global_load_lds((gptr_t)(g), (lptr_t)(l), 16, 0, 0)

__device__ __forceinline__ f32x4 mfma16(bf16x8 a, bf16x8 b, f32x4 c) {
    return __builtin_amdgcn_mfma_f32_16x16x32_bf16(a, b, c, 0, 0, 0);
}

// ---------------- fp32 -> bf16 convert (vectorized) ----------------
__global__ void k_cvt(const float* __restrict__ src, bf16* __restrict__ dst, int n4) {
    int i = blockIdx.x * blockDim.x + threadIdx.x;
    if (i < n4) {
        float4 v = ((const float4*)src)[i];
        bf16x4 o;
        o[0] = (__bf16)v.x; o[1] = (__bf16)v.y; o[2] = (__bf16)v.z; o[3] = (__bf16)v.w;
        *(bf16x4*)(dst + i * 4) = o;
    }
}

// ---------------- RoPE cos/sin table: [S][32] fp32 ----------------
__global__ void k_tab(float* __restrict__ cosT, float* __restrict__ sinT) {
    int i = blockIdx.x * blockDim.x + threadIdx.x;
    if (i >= S_ * 32) return;
    int s = i >> 5, d = i & 31;
    float inv = powf(10000.0f, -(float)d * (1.0f / 32.0f));
    float ang = (float)s * inv;
    cosT[i] = cosf(ang);
    sinT[i] = sinf(ang);
}

// ---------------- GEMM: out[m][n] = sum_k A[m][k] * W[n][k] ----------------
// 128x128 tile, 4 waves (2x2 of 64x64), BK=32, 16x16x32 bf16 MFMA.
// EPI 0: n in [0,3072) -> q/k/v in (B,NH,S,HD) bf16 with RoPE on q,k.
// EPI 1: fp32 row-major out (N=1024).
template<int EPI>
__global__ __launch_bounds__(256) void k_gemm(
        const bf16* __restrict__ A, const bf16* __restrict__ Bw,
        bf16* __restrict__ q_out, bf16* __restrict__ k_out, bf16* __restrict__ v_out,
        const float* __restrict__ cosT, const float* __restrict__ sinT,
        float* __restrict__ fout) {
    __shared__ bf16 As[128 * 32];
    __shared__ bf16 Bs[128 * 32];
    const int t = threadIdx.x, l = t & 63, w = t >> 6;
    const int lr = l & 15, hi = l >> 4;
    const int m0 = blockIdx.y * 128, n0 = blockIdx.x * 128;
    const int wr = (w >> 1) * 64, wc = (w & 1) * 64;
    f32x4 acc[4][4] = {};

    for (int k0 = 0; k0 < 1024; k0 += 32) {
        __syncthreads();
#pragma unroll
        for (int i = 0; i < 2; ++i) {
            int o = i * 4096 + t * 16;          // byte offset in 8KB tile
            int row = o >> 6, colb = o & 63;    // 64B per row (32 bf16)
            GLOAD_LDS16((const char*)A + ((size_t)(m0 + row) * 1024 + k0) * 2 + colb,
                        (char*)As + o);
            GLOAD_LDS16((const char*)Bw + ((size_t)(n0 + row) * 1024 + k0) * 2 + colb,
                        (char*)Bs + o);
        }
        __syncthreads();
        bf16x8 af[4], bfr[4];
#pragma unroll
        for (int mi = 0; mi < 4; ++mi)
            af[mi] = *(const bf16x8*)&As[(wr + mi * 16 + lr) * 32 + hi * 8];
#pragma unroll
        for (int ni = 0; ni < 4; ++ni)
            bfr[ni] = *(const bf16x8*)&Bs[(wc + ni * 16 + lr) * 32 + hi * 8];
#pragma unroll
        for (int mi = 0; mi < 4; ++mi)
#pragma unroll
            for (int ni = 0; ni < 4; ++ni)
                acc[mi][ni] = mfma16(af[mi], bfr[ni], acc[mi][ni]);
    }

    // D layout (m89-verified): col = lr, row = hi*4 + reg
    if (EPI == 0) {
        const int nbase = n0 + wc;               // 64-aligned -> one head
        const int which = nbase >> 10;           // 0:q 1:k 2:v
        const int head = (nbase & 1023) >> 6;
        bf16* dst = which == 0 ? q_out : (which == 1 ? k_out : v_out);
#pragma unroll
        for (int mi = 0; mi < 4; ++mi) {
#pragma unroll
            for (int r = 0; r < 4; ++r) {
                int m = m0 + wr + mi * 16 + hi * 4 + r;
                int bb = m >> 11, s = m & 2047;
                size_t base = (((size_t)bb * NH_ + head) * S_ + s) * HD_;
                if (which == 2) {
#pragma unroll
                    for (int ni = 0; ni < 4; ++ni)
                        dst[base + ni * 16 + lr] = (__bf16)acc[mi][ni][r];
                } else {
#pragma unroll
                    for (int ni = 0; ni < 2; ++ni) {
                        int d = ni * 16 + lr;            // 0..31
                        float c = cosT[s * 32 + d], sn = sinT[s * 32 + d];
                        float x1 = acc[mi][ni][r], x2 = acc[mi][ni + 2][r];
                        dst[base + d]      = (__bf16)(x1 * c - x2 * sn);
                        dst[base + d + 32] = (__bf16)(x2 * c + x1 * sn);
                    }
                }
            }
        }
    } else {
#pragma unroll
        for (int mi = 0; mi < 4; ++mi)
#pragma unroll
            for (int ni = 0; ni < 4; ++ni)
#pragma unroll
                for (int r = 0; r < 4; ++r)
                    fout[(size_t)(m0 + wr + mi * 16 + hi * 4 + r) * 1024
                         + (n0 + wc + ni * 16 + lr)] = acc[mi][ni][r];
    }
}

// ---------------- Flash attention (swapped-operand) ----------------
// Block: 4 waves x 16 q-rows = 64 q rows; KV tiles of 32.
// S^T = mfma(K, Q): lane owns q-col = lr; kv rows = 16*h + hi*4 + reg.
// PV: O^T = mfma(V^T, P^T) with P^T already lane-resident.
__global__ __launch_bounds__(256) void k_attn(
        const bf16* __restrict__ qr, const bf16* __restrict__ kr,
        const bf16* __restrict__ vr, const int* __restrict__ mask,
        bf16* __restrict__ aout) {
    __shared__ bf16 Ks[32 * 64];     // XOR-swizzled rows
    __shared__ bf16 Vt[64 * 36];     // transposed [d][kv], padded to 36
    const int t = threadIdx.x, l = t & 63, w = t >> 6;
    const int lr = l & 15, hi = l >> 4;
    const int bh = blockIdx.y, b = bh >> 4, head = bh & 15;
    const int qrow = blockIdx.x * 64 + w * 16 + lr;

    const bf16* Qb = qr + ((size_t)bh * S_ + qrow) * HD_;
    bf16x8 qf0 = *(const bf16x8*)(Qb + hi * 8);
    bf16x8 qf1 = *(const bf16x8*)(Qb + 32 + hi * 8);
#pragma unroll
    for (int j = 0; j < 8; ++j) {    // fold 1/sqrt(64)=0.125 into Q (exact in bf16)
        qf0[j] = (__bf16)((float)qf0[j] * 0.125f);
        qf1[j] = (__bf16)((float)qf1[j] * 0.125f);
    }

    f32x4 acc[4] = {};
    float mrun = -1e30f, lrun = 0.0f;

    const int srow = t >> 3, scolb = (t & 7) * 16;
    const int ssw = scolb ^ ((srow & 7) << 4);            // K swizzle (involution)
    const char* kbase = (const char*)(kr + (size_t)bh * S_ * HD_);
    const int vkv = t & 31, vc0 = (t >> 5) * 8;
    const bf16* vbase = vr + (size_t)bh * S_ * HD_;
    const int* mrow = mask + b * S_;

    for (int kv0 = 0; kv0 < S_; kv0 += 32) {
        __syncthreads();
        GLOAD_LDS16(kbase + (size_t)(kv0 + srow) * 128 + ssw, (char*)Ks + t * 16);
        bf16x8 v8 = *(const bf16x8*)(vbase + (size_t)(kv0 + vkv) * 64 + vc0);
#pragma unroll
        for (int i = 0; i < 8; ++i) Vt[(vc0 + i) * 36 + vkv] = v8[i];
        __syncthreads();

        f32x4 st0 = {0.f, 0.f, 0.f, 0.f}, st1 = {0.f, 0.f, 0.f, 0.f};
#pragma unroll
        for (int half = 0; half < 2; ++half) {
            int cb = half * 64 + hi * 16;
            int r0 = lr, r1 = 16 + lr;
            bf16x8 kf0 = *(const bf16x8*)((const char*)Ks + r0 * 128 + (cb ^ ((r0 & 7) << 4)));
            bf16x8 kf1 = *(const bf16x8*)((const char*)Ks + r1 * 128 + (cb ^ ((r1 & 7) << 4)));
            bf16x8 qh = half ? qf1 : qf0;
            st0 = mfma16(kf0, qh, st0);
            st1 = mfma16(kf1, qh, st1);
        }

        int mv = mrow[kv0 + (l & 31)];
#pragma unroll
        for (int r = 0; r < 4; ++r) {
            int ok0 = __shfl(mv, hi * 4 + r);
            int ok1 = __shfl(mv, 16 + hi * 4 + r);
            st0[r] = ok0 ? st0[r] : -1e30f;
            st1[r] = ok1 ? st1[r] : -1e30f;
        }

        float tmax = st0[0];
#pragma unroll
        for (int r = 1; r < 4; ++r) tmax = fmaxf(tmax, st0[r]);
#pragma unroll
        for (int r = 0; r < 4; ++r) tmax = fmaxf(tmax, st1[r]);
        tmax = fmaxf(tmax, __shfl_xor(tmax, 16));
        tmax = fmaxf(tmax, __shfl_xor(tmax, 32));
        float mnew = fmaxf(mrun, tmax);
        float corr = __expf(mrun - mnew);
        float p0[4], p1[4], tsum = 0.f;
#pragma unroll
        for (int r = 0; r < 4; ++r) {
            p0[r] = __expf(st0[r] - mnew);
            p1[r] = __expf(st1[r] - mnew);
            tsum += p0[r] + p1[r];
        }
        tsum += __shfl_xor(tsum, 16);
        tsum += __shfl_xor(tsum, 32);
        lrun = lrun * corr + tsum;
        mrun = mnew;

        bf16x8 pB;
        pB[0] = (__bf16)p0[0]; pB[1] = (__bf16)p0[1]; pB[2] = (__bf16)p0[2]; pB[3] = (__bf16)p0[3];
        pB[4] = (__bf16)p1[0]; pB[5] = (__bf16)p1[1]; pB[6] = (__bf16)p1[2]; pB[7] = (__bf16)p1[3];

#pragma unroll
        for (int dt = 0; dt < 4; ++dt)
#pragma unroll
            for (int r = 0; r < 4; ++r) acc[dt][r] *= corr;

#pragma unroll
        for (int dt = 0; dt < 4; ++dt) {
            const bf16* vrow = &Vt[(dt * 16 + lr) * 36];
            bf16x4 va = *(const bf16x4*)(vrow + hi * 4);
            bf16x4 vb = *(const bf16x4*)(vrow + 16 + hi * 4);
            bf16x8 vf;
            vf[0] = va[0]; vf[1] = va[1]; vf[2] = va[2]; vf[3] = va[3];
            vf[4] = vb[0]; vf[5] = vb[1]; vf[6] = vb[2]; vf[7] = vb[3];
            acc[dt] = mfma16(vf, pB, acc[dt]);
        }
    }

    float inv = 1.0f / lrun;
    size_t obase = ((size_t)(b * S_ + qrow)) * H_ + head * HD_;
#pragma unroll
    for (int dt = 0; dt < 4; ++dt)
#pragma unroll
        for (int r = 0; r < 4; ++r) {
            int d = dt * 16 + hi * 4 + r;
            aout[obase + d] = (__bf16)(acc[dt][r] * inv);
        }
}

extern "C" void kernel_launch(void* const* d_in, const int* in_sizes, int n_in,
                              void* d_out, int out_size, void* d_ws, size_t ws_size,
                              hipStream_t stream) {
    const float* x  = (const float*)d_in[0];
    const int* mask = (const int*)d_in[1];
    const float* Wq = (const float*)d_in[2];
    const float* Wk = (const float*)d_in[3];
    const float* Wv = (const float*)d_in[4];
    const float* Wo = (const float*)d_in[5];
    float* out = (float*)d_out;

    char* ws = (char*)d_ws;
    bf16* xb    = (bf16*)ws;                               // 16 MB (reused as attn out)
    bf16* wqkv  = (bf16*)(ws + (size_t)16 * 1048576);      // 6 MB
    bf16* wob   = (bf16*)(ws + (size_t)22 * 1048576);      // 2 MB
    bf16* qr    = (bf16*)(ws + (size_t)24 * 1048576);      // 16 MB
    bf16* kr    = (bf16*)(ws + (size_t)40 * 1048576);      // 16 MB
    bf16* vr    = (bf16*)(ws + (size_t)56 * 1048576);      // 16 MB
    float* cosT = (float*)(ws + (size_t)72 * 1048576);     // 256 KB
    float* sinT = (float*)(ws + (size_t)72 * 1048576 + 262144);

    // converts
    k_cvt<<<2097152 / 256, 256, 0, stream>>>(x, xb, 2097152);
    k_cvt<<<262144 / 256, 256, 0, stream>>>(Wq, wqkv, 262144);
    k_cvt<<<262144 / 256, 256, 0, stream>>>(Wk, wqkv + 1048576, 262144);
    k_cvt<<<262144 / 256, 256, 0, stream>>>(Wv, wqkv + 2097152, 262144);
    k_cvt<<<262144 / 256, 256, 0, stream>>>(Wo, wob, 262144);
    k_tab<<<256, 256, 0, stream>>>(cosT, sinT);

    // QKV projection + RoPE + relayout
    k_gemm<0><<<dim3(24, 64), 256, 0, stream>>>(xb, wqkv, qr, kr, vr, cosT, sinT, nullptr);

    // flash attention -> (B,S,H) bf16 (reuse xb region)
    k_attn<<<dim3(32, 64), 256, 0, stream>>>(qr, kr, vr, mask, xb);

    // output projection -> fp32
    k_gemm<1><<<dim3(8, 64), 256, 0, stream>>>(xb, wob, nullptr, nullptr, nullptr,
                                               nullptr, nullptr, out);
}